// Round 7
// baseline (357.753 us; speedup 1.0000x reference)
//
#include <hip/hip_runtime.h>
#include <hip/hip_fp16.h>

#define NUM_GRAPHS 8192
#define BSHIFT 12
#define BSIZE 4096     // nodes per bucket
#define CHUNK 8192     // edges per chunk
#define SBLOCKS 1024   // scatter-role blocks
#define HBLOCKS 2048   // h-compute-role blocks

// ===== Pass 1 (fused): edge scatter into dst-buckets  ||  h = x @ W =========
// Role-split by blockIdx%3: 1/3 scatter (atomic/latency-bound), 2/3 h-compute
// (BW-bound) — co-resident on each CU so the memory pipe is never idle.
__global__ void __launch_bounds__(256)
fused_scatter_h_kernel(const int* __restrict__ src, const int* __restrict__ dst,
                       int E, int nchunks, int NBUK, int cap,
                       unsigned* __restrict__ cursor, unsigned* __restrict__ slab,
                       const float* __restrict__ x, const float* __restrict__ W,
                       float* __restrict__ h, int N) {
    __shared__ unsigned cnt[256];
    __shared__ unsigned lbase[256];   // exclusive chunk-local base per bucket
    __shared__ unsigned sbase[256];   // global reservation base per bucket
    __shared__ unsigned staged[CHUNK];
    __shared__ unsigned char sbuck[CHUNK];
    __shared__ unsigned s_tot;

    int bid = blockIdx.x;
    int rem = bid % 3;
    int grp = bid / 3;
    int tid = threadIdx.x;

    if (rem == 0) {
        // ---------------- scatter role: block grp in [0, SBLOCKS) ----------
        const int4* s4 = (const int4*)src;
        const int4* d4 = (const int4*)dst;
        int E4 = E >> 2;
        for (int chunk = grp; chunk < nchunks; chunk += SBLOCKS) {
            cnt[tid] = 0; __syncthreads();
            int b4 = chunk * (CHUNK / 4);
            int4 vd[8], vs[8];
            unsigned short r[32];
            #pragma unroll
            for (int k = 0; k < 8; ++k) {
                int idx = b4 + k * 256 + tid;
                if (idx < E4) { vd[k] = d4[idx]; vs[k] = s4[idx]; }
                else          { vd[k] = make_int4(-1, -1, -1, -1); }
            }
            #pragma unroll
            for (int k = 0; k < 8; ++k) {
                if (vd[k].x >= 0) {
                    r[4*k+0] = (unsigned short)atomicAdd(&cnt[vd[k].x >> BSHIFT], 1u);
                    r[4*k+1] = (unsigned short)atomicAdd(&cnt[vd[k].y >> BSHIFT], 1u);
                    r[4*k+2] = (unsigned short)atomicAdd(&cnt[vd[k].z >> BSHIFT], 1u);
                    r[4*k+3] = (unsigned short)atomicAdd(&cnt[vd[k].w >> BSHIFT], 1u);
                }
            }
            __syncthreads();
            // inclusive Hillis-Steele scan of cnt -> lbase
            lbase[tid] = cnt[tid]; __syncthreads();
            #pragma unroll
            for (int off = 1; off < 256; off <<= 1) {
                unsigned a = (tid >= off) ? lbase[tid - off] : 0u;
                __syncthreads();
                lbase[tid] += a;
                __syncthreads();
            }
            if (tid == 255) s_tot = lbase[255];
            if (tid < NBUK && cnt[tid]) sbase[tid] = atomicAdd(&cursor[tid], cnt[tid]);
            unsigned excl = lbase[tid] - cnt[tid];
            __syncthreads();
            lbase[tid] = excl;
            __syncthreads();

            // stage entries bucket-sorted in LDS
            #pragma unroll
            for (int k = 0; k < 8; ++k) {
                if (vd[k].x >= 0) {
                    int d0 = vd[k].x, d1 = vd[k].y, d2 = vd[k].z, d3 = vd[k].w;
                    unsigned b0 = (unsigned)d0 >> BSHIFT, b1 = (unsigned)d1 >> BSHIFT;
                    unsigned b2 = (unsigned)d2 >> BSHIFT, b3 = (unsigned)d3 >> BSHIFT;
                    unsigned p0 = lbase[b0] + r[4*k+0];
                    unsigned p1 = lbase[b1] + r[4*k+1];
                    unsigned p2 = lbase[b2] + r[4*k+2];
                    unsigned p3 = lbase[b3] + r[4*k+3];
                    staged[p0] = ((unsigned)(d0 & (BSIZE - 1)) << 20) | (unsigned)vs[k].x;
                    staged[p1] = ((unsigned)(d1 & (BSIZE - 1)) << 20) | (unsigned)vs[k].y;
                    staged[p2] = ((unsigned)(d2 & (BSIZE - 1)) << 20) | (unsigned)vs[k].z;
                    staged[p3] = ((unsigned)(d3 & (BSIZE - 1)) << 20) | (unsigned)vs[k].w;
                    sbuck[p0] = (unsigned char)b0;
                    sbuck[p1] = (unsigned char)b1;
                    sbuck[p2] = (unsigned char)b2;
                    sbuck[p3] = (unsigned char)b3;
                }
            }
            __syncthreads();

            // flush: consecutive lanes -> consecutive slab addresses
            unsigned tot = s_tot;
            for (unsigned pos = tid; pos < tot; pos += 256) {
                unsigned b = sbuck[pos];
                unsigned gp = sbase[b] + (pos - lbase[b]);
                if (gp < (unsigned)cap) slab[(size_t)b * cap + gp] = staged[pos];
            }
            __syncthreads();
        }
        if (grp == 0 && tid < (E & 3)) {
            int i = (E & ~3) + tid;
            int d = dst[i];
            unsigned p = atomicAdd(&cursor[d >> BSHIFT], 1u);
            if (p < (unsigned)cap)
                slab[(size_t)(d >> BSHIFT) * cap + p] =
                    ((unsigned)(d & (BSIZE - 1)) << 20) | (unsigned)src[i];
        }
    } else {
        // ---------------- h role: block hid in [0, HBLOCKS) ----------------
        int hid = grp * 2 + (rem - 1);
        int wave = tid >> 6;
        int lane = tid & 63;
        int half = lane >> 5;
        int l32  = lane & 31;
        float4 wv = ((const float4*)W)[l32];
        for (int base = hid * 8; base < N; base += HBLOCKS * 8) {
            int node = base + wave * 2 + half;
            if (node < N) {
                float4 xv = ((const float4*)(x + (size_t)node * 128))[l32];
                float v = xv.x * wv.x + xv.y * wv.y + xv.z * wv.z + xv.w * wv.w;
                #pragma unroll
                for (int d = 16; d >= 1; d >>= 1) v += __shfl_xor(v, d);
                if (l32 == 0) h[node] = v;
            }
        }
    }
}

// ===== Pass 2: per-bucket degree hist -> dinv -> hsh/pkw (fused finalize) ===
__global__ void __launch_bounds__(1024)
hist_finalize_kernel(const unsigned* __restrict__ slab, int cap,
                     const unsigned* __restrict__ cursor,
                     const float* __restrict__ h, const int* __restrict__ batch,
                     unsigned short* __restrict__ hsh, unsigned* __restrict__ pkw,
                     int N) {
    __shared__ unsigned hist[BSIZE];
    int b = blockIdx.x, tid = threadIdx.x;
    unsigned n = cursor[b]; if (n > (unsigned)cap) n = cap;
    for (int t = tid; t < BSIZE; t += 1024) hist[t] = 0;
    __syncthreads();
    const unsigned* s = slab + (size_t)b * cap;
    for (unsigned i = tid; i < n; i += 1024) atomicAdd(&hist[s[i] >> 20], 1u);
    __syncthreads();
    int base = b << BSHIFT;
    int lim = N - base; if (lim > BSIZE) lim = BSIZE;
    for (int t = tid; t < lim; t += 1024) {
        float di = rsqrtf((float)(hist[t] + 1u));   // +1 self-loop
        hsh[base + t] = __half_as_ushort(__float2half(di * h[base + t]));
        pkw[base + t] = ((unsigned)batch[base + t] << 16) |
                        __half_as_ushort(__float2half(di));
    }
}

// ===== Pass 3: per-bucket aggregation (edges + self-loops) -> pooled ========
__global__ void __launch_bounds__(1024)
aggregate_kernel(const unsigned* __restrict__ slab, int cap,
                 const unsigned* __restrict__ cursor,
                 const unsigned* __restrict__ pkw,
                 const unsigned short* __restrict__ hsh,
                 float* __restrict__ pooled, int N) {
    __shared__ float pool[NUM_GRAPHS];
    __shared__ unsigned pkw_s[BSIZE];
    int b = blockIdx.x, tid = threadIdx.x;
    int base = b << BSHIFT;
    int lim = N - base; if (lim > BSIZE) lim = BSIZE;

    for (int t = tid; t < NUM_GRAPHS; t += 1024) pool[t] = 0.0f;
    for (int t = tid; t < BSIZE; t += 1024) pkw_s[t] = (t < lim) ? pkw[base + t] : 0u;
    __syncthreads();

    // self-loop terms
    for (int t = tid; t < lim; t += 1024) {
        unsigned w = pkw_s[t];
        float di = __half2float(__ushort_as_half((unsigned short)(w & 0xFFFFu)));
        float c = di * __half2float(__ushort_as_half(hsh[base + t]));
        atomicAdd(&pool[w >> 16], c);
    }

    // edge terms
    unsigned n = cursor[b]; if (n > (unsigned)cap) n = cap;
    const unsigned* s = slab + (size_t)b * cap;
    for (unsigned i = tid; i < n; i += 1024) {
        unsigned e = s[i];
        unsigned w = pkw_s[e >> 20];
        float hv = __half2float(__ushort_as_half(hsh[e & 0xFFFFFu]));
        float di = __half2float(__ushort_as_half((unsigned short)(w & 0xFFFFu)));
        atomicAdd(&pool[w >> 16], hv * di);
    }
    __syncthreads();

    // batch sorted -> bucket spans [g_lo, g_hi]; flush only that range
    int g_lo = (int)(pkw_s[0] >> 16);
    int g_hi = (lim > 0) ? (int)(pkw_s[lim - 1] >> 16) : g_lo;
    for (int g = g_lo + tid; g <= g_hi; g += 1024) atomicAdd(&pooled[g], pool[g]);
}

// ===== Pass 4: affine ======================================================
__global__ void out_kernel(const float* __restrict__ pooled,
                           const float* __restrict__ pp_w,
                           const float* __restrict__ pp_b,
                           float* __restrict__ out) {
    int g = blockIdx.x * blockDim.x + threadIdx.x;
    if (g < NUM_GRAPHS) out[g] = pooled[g] * pp_w[0] + pp_b[0];
}

// ===== Fallback path (tiny ws / oversized N): correctness only =============
__global__ void deg_atomic_kernel(const int* __restrict__ dst, int E,
                                  unsigned* __restrict__ deg) {
    int tid = blockIdx.x * blockDim.x + threadIdx.x;
    int stride = gridDim.x * blockDim.x;
    for (int i = tid; i < E; i += stride) atomicAdd(&deg[dst[i]], 1u);
}

__global__ void node_fb_kernel(const float* __restrict__ x,
                               const float* __restrict__ W,
                               const unsigned* __restrict__ deg,
                               const int* __restrict__ batch,
                               unsigned short* __restrict__ hsh,
                               unsigned* __restrict__ pkw, int N) {
    int gtid = blockIdx.x * blockDim.x + threadIdx.x;
    int wave = gtid >> 6;
    int lane = threadIdx.x & 63;
    int half = lane >> 5;
    int l32  = lane & 31;
    int node = wave * 2 + half;
    if (node >= N) return;
    const float4* xr = (const float4*)(x + (size_t)node * 128);
    float4 xv = xr[l32];
    float4 wv = ((const float4*)W)[l32];
    float v = xv.x * wv.x + xv.y * wv.y + xv.z * wv.z + xv.w * wv.w;
    #pragma unroll
    for (int d = 16; d >= 1; d >>= 1) v += __shfl_xor(v, d);
    if (l32 == 0) {
        float di = rsqrtf((float)(deg[node] + 1u));
        hsh[node] = __half_as_ushort(__float2half(di * v));
        pkw[node] = ((unsigned)batch[node] << 16) | __half_as_ushort(__float2half(di));
    }
}

__global__ void pool_self_fb_kernel(const unsigned short* __restrict__ hsh,
                                    const unsigned* __restrict__ pkw,
                                    float* __restrict__ pooled, int N) {
    int i = blockIdx.x * blockDim.x + threadIdx.x;
    if (i >= N) return;
    unsigned w = pkw[i];
    float di = __half2float(__ushort_as_half((unsigned short)(w & 0xFFFFu)));
    atomicAdd(&pooled[w >> 16], di * __half2float(__ushort_as_half(hsh[i])));
}

__global__ void __launch_bounds__(512)
edge_direct_kernel(const int* __restrict__ src, const int* __restrict__ dst, int E,
                   const unsigned short* __restrict__ hsh,
                   const unsigned* __restrict__ pkw,
                   float* __restrict__ pooled) {
    __shared__ float pool[NUM_GRAPHS];
    for (int g = threadIdx.x; g < NUM_GRAPHS; g += 512) pool[g] = 0.0f;
    __syncthreads();
    int tid = blockIdx.x * 512 + threadIdx.x;
    int stride = gridDim.x * 512;
    for (int i = tid; i < E; i += stride) {
        unsigned w = pkw[dst[i]];
        float c = __half2float(__ushort_as_half(hsh[src[i]])) *
                  __half2float(__ushort_as_half((unsigned short)(w & 0xFFFFu)));
        atomicAdd(&pool[w >> 16], c);
    }
    __syncthreads();
    for (int g = threadIdx.x; g < NUM_GRAPHS; g += 512)
        if (pool[g] != 0.0f) atomicAdd(&pooled[g], pool[g]);
}

extern "C" void kernel_launch(void* const* d_in, const int* in_sizes, int n_in,
                              void* d_out, int out_size, void* d_ws, size_t ws_size,
                              hipStream_t stream) {
    const float* x    = (const float*)d_in[0];
    const float* W    = (const float*)d_in[1];
    const float* pp_w = (const float*)d_in[2];
    const float* pp_b = (const float*)d_in[3];
    const int*   ei   = (const int*)d_in[4];
    const int*   batch= (const int*)d_in[5];
    float* out = (float*)d_out;

    const int E = in_sizes[4] / 2;
    const int N = in_sizes[5];
    const int* src = ei;
    const int* dst = ei + E;
    int NBUK = (N + BSIZE - 1) >> BSHIFT;

    char* ws = (char*)d_ws;
    size_t off = 0;
    auto alloc = [&](size_t bytes) {
        size_t o = off; off = (off + bytes + 255) & ~(size_t)255; return o;
    };
    size_t deg_off    = alloc((size_t)N * 4);     // fallback only
    size_t h_off      = alloc((size_t)N * 4);
    size_t hsh_off    = alloc((size_t)N * 2);
    size_t pkw_off    = alloc((size_t)N * 4);
    size_t pooled_off = alloc((size_t)NUM_GRAPHS * 4);
    size_t cursor_off = alloc(1024);

    int cap = E / NBUK + E / NBUK / 8 + 2048;   // mean + ~14% headroom (>30 sigma)
    size_t slab_off = alloc((size_t)NBUK * (size_t)cap * 4);

    bool slab_ok = (NBUK <= 256) && (N <= (1 << 20)) && (off <= ws_size);

    unsigned*       deg    = (unsigned*)(ws + deg_off);
    float*          h      = (float*)(ws + h_off);
    unsigned short* hsh    = (unsigned short*)(ws + hsh_off);
    unsigned*       pkw    = (unsigned*)(ws + pkw_off);
    float*          pooled = (float*)(ws + pooled_off);
    unsigned*       cursor = (unsigned*)(ws + cursor_off);
    unsigned*       slab   = (unsigned*)(ws + slab_off);

    hipMemsetAsync(pooled, 0, (size_t)NUM_GRAPHS * 4, stream);

    if (slab_ok) {
        hipMemsetAsync(cursor, 0, 1024, stream);
        int E4 = E >> 2;
        int nchunks = (E4 + (CHUNK / 4 - 1)) / (CHUNK / 4);
        fused_scatter_h_kernel<<<SBLOCKS + HBLOCKS, 256, 0, stream>>>(
            src, dst, E, nchunks, NBUK, cap, cursor, slab, x, W, h, N);
        hist_finalize_kernel<<<NBUK, 1024, 0, stream>>>(slab, cap, cursor, h,
                                                        batch, hsh, pkw, N);
        aggregate_kernel<<<NBUK, 1024, 0, stream>>>(slab, cap, cursor, pkw, hsh,
                                                    pooled, N);
    } else {
        hipMemsetAsync(deg, 0, (size_t)N * 4, stream);
        deg_atomic_kernel<<<2048, 256, 0, stream>>>(dst, E, deg);
        int node_blocks = (N + 7) / 8;
        node_fb_kernel<<<node_blocks, 256, 0, stream>>>(x, W, deg, batch, hsh, pkw, N);
        pool_self_fb_kernel<<<(N + 255) / 256, 256, 0, stream>>>(hsh, pkw, pooled, N);
        edge_direct_kernel<<<512, 512, 0, stream>>>(src, dst, E, hsh, pkw, pooled);
    }

    out_kernel<<<(NUM_GRAPHS + 255) / 256, 256, 0, stream>>>(pooled, pp_w, pp_b, out);
}

// Round 8
// 316.182 us; speedup vs baseline: 1.1315x; 1.1315x over previous
//
#include <hip/hip_runtime.h>
#include <hip/hip_fp16.h>

#define NUM_GRAPHS 8192
#define BSHIFT 12
#define BSIZE 4096     // nodes per bucket
#define CHUNK 8192     // edges per chunk
#define NGRP 32        // cursor/slab groups (breaks same-address atomic chains)

// ===== Pass 1: h = x @ W (standalone, high occupancy, BW-bound) ============
__global__ void node_h_kernel(const float* __restrict__ x,
                              const float* __restrict__ W,
                              float* __restrict__ h, int N) {
    int gtid = blockIdx.x * blockDim.x + threadIdx.x;
    int wave = gtid >> 6;
    int lane = threadIdx.x & 63;
    int half = lane >> 5;
    int l32  = lane & 31;
    int node = wave * 2 + half;
    if (node >= N) return;
    float4 xv = ((const float4*)(x + (size_t)node * 128))[l32];
    float4 wv = ((const float4*)W)[l32];
    float v = xv.x * wv.x + xv.y * wv.y + xv.z * wv.z + xv.w * wv.w;
    #pragma unroll
    for (int d = 16; d >= 1; d >>= 1) v += __shfl_xor(v, d);
    if (l32 == 0) h[node] = v;
}

// ===== Pass 2: scatter packed (dst_lo<<20 | src) into per-(group,bucket) ====
// sub-slabs. Group-private cursors cut same-address atomic chain depth ~32x.
__global__ void __launch_bounds__(256)
pair_scatter_kernel(const int* __restrict__ src, const int* __restrict__ dst,
                    int E, int nchunks, int NBUK, int capG,
                    unsigned* __restrict__ cursor, unsigned* __restrict__ slab) {
    __shared__ unsigned cnt[256];
    __shared__ unsigned lbase[256];   // exclusive chunk-local base per bucket
    __shared__ unsigned sbase[256];   // global reservation base per bucket
    __shared__ unsigned staged[CHUNK];
    __shared__ unsigned char sbuck[CHUNK];
    __shared__ unsigned s_tot;

    const int4* s4 = (const int4*)src;
    const int4* d4 = (const int4*)dst;
    int E4 = E >> 2;
    int tid = threadIdx.x;
    int g = blockIdx.x & (NGRP - 1);

    for (int chunk = blockIdx.x; chunk < nchunks; chunk += gridDim.x) {
        cnt[tid] = 0; __syncthreads();
        int b4 = chunk * (CHUNK / 4);
        int4 vd[8], vs[8];
        unsigned short r[32];
        #pragma unroll
        for (int k = 0; k < 8; ++k) {
            int idx = b4 + k * 256 + tid;
            if (idx < E4) { vd[k] = d4[idx]; vs[k] = s4[idx]; }
            else          { vd[k] = make_int4(-1, -1, -1, -1); }
        }
        #pragma unroll
        for (int k = 0; k < 8; ++k) {
            if (vd[k].x >= 0) {
                r[4*k+0] = (unsigned short)atomicAdd(&cnt[vd[k].x >> BSHIFT], 1u);
                r[4*k+1] = (unsigned short)atomicAdd(&cnt[vd[k].y >> BSHIFT], 1u);
                r[4*k+2] = (unsigned short)atomicAdd(&cnt[vd[k].z >> BSHIFT], 1u);
                r[4*k+3] = (unsigned short)atomicAdd(&cnt[vd[k].w >> BSHIFT], 1u);
            }
        }
        __syncthreads();
        // inclusive Hillis-Steele scan of cnt -> lbase
        lbase[tid] = cnt[tid]; __syncthreads();
        #pragma unroll
        for (int off = 1; off < 256; off <<= 1) {
            unsigned a = (tid >= off) ? lbase[tid - off] : 0u;
            __syncthreads();
            lbase[tid] += a;
            __syncthreads();
        }
        if (tid == 255) s_tot = lbase[255];
        // reservation in group-private cursor row (coalesced, low chain depth)
        if (tid < NBUK && cnt[tid]) sbase[tid] = atomicAdd(&cursor[g * 256 + tid], cnt[tid]);
        unsigned excl = lbase[tid] - cnt[tid];
        __syncthreads();
        lbase[tid] = excl;
        __syncthreads();

        // stage entries bucket-sorted in LDS
        #pragma unroll
        for (int k = 0; k < 8; ++k) {
            if (vd[k].x >= 0) {
                int d0 = vd[k].x, d1 = vd[k].y, d2 = vd[k].z, d3 = vd[k].w;
                unsigned b0 = (unsigned)d0 >> BSHIFT, b1 = (unsigned)d1 >> BSHIFT;
                unsigned b2 = (unsigned)d2 >> BSHIFT, b3 = (unsigned)d3 >> BSHIFT;
                unsigned p0 = lbase[b0] + r[4*k+0];
                unsigned p1 = lbase[b1] + r[4*k+1];
                unsigned p2 = lbase[b2] + r[4*k+2];
                unsigned p3 = lbase[b3] + r[4*k+3];
                staged[p0] = ((unsigned)(d0 & (BSIZE - 1)) << 20) | (unsigned)vs[k].x;
                staged[p1] = ((unsigned)(d1 & (BSIZE - 1)) << 20) | (unsigned)vs[k].y;
                staged[p2] = ((unsigned)(d2 & (BSIZE - 1)) << 20) | (unsigned)vs[k].z;
                staged[p3] = ((unsigned)(d3 & (BSIZE - 1)) << 20) | (unsigned)vs[k].w;
                sbuck[p0] = (unsigned char)b0;
                sbuck[p1] = (unsigned char)b1;
                sbuck[p2] = (unsigned char)b2;
                sbuck[p3] = (unsigned char)b3;
            }
        }
        __syncthreads();

        // flush: consecutive lanes -> consecutive sub-slab addresses
        unsigned tot = s_tot;
        for (unsigned pos = tid; pos < tot; pos += 256) {
            unsigned b = sbuck[pos];
            unsigned gp = sbase[b] + (pos - lbase[b]);
            if (gp < (unsigned)capG)
                slab[((size_t)g * NBUK + b) * capG + gp] = staged[pos];
        }
        __syncthreads();
    }
    if (blockIdx.x == 0 && tid < (E & 3)) {
        int i = (E & ~3) + tid;
        int d = dst[i];
        unsigned b = (unsigned)d >> BSHIFT;
        unsigned p = atomicAdd(&cursor[b], 1u);   // group 0 row
        if (p < (unsigned)capG)
            slab[(size_t)b * capG + p] =
                ((unsigned)(d & (BSIZE - 1)) << 20) | (unsigned)src[i];
    }
}

// ===== Pass 3: per-bucket degree hist (over NGRP segments) -> hsh/pkw =======
__global__ void __launch_bounds__(1024)
hist_finalize_kernel(const unsigned* __restrict__ slab, int capG,
                     const unsigned* __restrict__ cursor,
                     const float* __restrict__ h, const int* __restrict__ batch,
                     unsigned short* __restrict__ hsh, unsigned* __restrict__ pkw,
                     int N, int NBUK) {
    __shared__ unsigned hist[BSIZE];
    int b = blockIdx.x, tid = threadIdx.x;
    for (int t = tid; t < BSIZE; t += 1024) hist[t] = 0;
    __syncthreads();
    for (int g = 0; g < NGRP; ++g) {
        unsigned n = cursor[g * 256 + b]; if (n > (unsigned)capG) n = capG;
        const unsigned* s = slab + ((size_t)g * NBUK + b) * capG;
        for (unsigned i = tid; i < n; i += 1024) atomicAdd(&hist[s[i] >> 20], 1u);
    }
    __syncthreads();
    int base = b << BSHIFT;
    int lim = N - base; if (lim > BSIZE) lim = BSIZE;
    for (int t = tid; t < lim; t += 1024) {
        float di = rsqrtf((float)(hist[t] + 1u));   // +1 self-loop
        hsh[base + t] = __half_as_ushort(__float2half(di * h[base + t]));
        pkw[base + t] = ((unsigned)batch[base + t] << 16) |
                        __half_as_ushort(__float2half(di));
    }
}

// ===== Pass 4: per-bucket aggregation (edges + self-loops) -> pooled ========
__global__ void __launch_bounds__(1024)
aggregate_kernel(const unsigned* __restrict__ slab, int capG,
                 const unsigned* __restrict__ cursor,
                 const unsigned* __restrict__ pkw,
                 const unsigned short* __restrict__ hsh,
                 float* __restrict__ pooled, int N, int NBUK) {
    __shared__ float pool[NUM_GRAPHS];
    __shared__ unsigned pkw_s[BSIZE];
    int b = blockIdx.x, tid = threadIdx.x;
    int base = b << BSHIFT;
    int lim = N - base; if (lim > BSIZE) lim = BSIZE;

    for (int t = tid; t < NUM_GRAPHS; t += 1024) pool[t] = 0.0f;
    for (int t = tid; t < BSIZE; t += 1024) pkw_s[t] = (t < lim) ? pkw[base + t] : 0u;
    __syncthreads();

    // self-loop terms
    for (int t = tid; t < lim; t += 1024) {
        unsigned w = pkw_s[t];
        float di = __half2float(__ushort_as_half((unsigned short)(w & 0xFFFFu)));
        float c = di * __half2float(__ushort_as_half(hsh[base + t]));
        atomicAdd(&pool[w >> 16], c);
    }

    // edge terms over the bucket's NGRP sub-slab segments
    for (int g = 0; g < NGRP; ++g) {
        unsigned n = cursor[g * 256 + b]; if (n > (unsigned)capG) n = capG;
        const unsigned* s = slab + ((size_t)g * NBUK + b) * capG;
        for (unsigned i = tid; i < n; i += 1024) {
            unsigned e = s[i];
            unsigned w = pkw_s[e >> 20];
            float hv = __half2float(__ushort_as_half(hsh[e & 0xFFFFFu]));
            float di = __half2float(__ushort_as_half((unsigned short)(w & 0xFFFFu)));
            atomicAdd(&pool[w >> 16], hv * di);
        }
    }
    __syncthreads();

    // batch sorted -> bucket spans [g_lo, g_hi]; flush only that range
    int g_lo = (int)(pkw_s[0] >> 16);
    int g_hi = (lim > 0) ? (int)(pkw_s[lim - 1] >> 16) : g_lo;
    for (int g = g_lo + tid; g <= g_hi; g += 1024) atomicAdd(&pooled[g], pool[g]);
}

// ===== Pass 5: affine ======================================================
__global__ void out_kernel(const float* __restrict__ pooled,
                           const float* __restrict__ pp_w,
                           const float* __restrict__ pp_b,
                           float* __restrict__ out) {
    int g = blockIdx.x * blockDim.x + threadIdx.x;
    if (g < NUM_GRAPHS) out[g] = pooled[g] * pp_w[0] + pp_b[0];
}

// ===== Fallback path (tiny ws / oversized N): correctness only =============
__global__ void deg_atomic_kernel(const int* __restrict__ dst, int E,
                                  unsigned* __restrict__ deg) {
    int tid = blockIdx.x * blockDim.x + threadIdx.x;
    int stride = gridDim.x * blockDim.x;
    for (int i = tid; i < E; i += stride) atomicAdd(&deg[dst[i]], 1u);
}

__global__ void node_fb_kernel(const float* __restrict__ x,
                               const float* __restrict__ W,
                               const unsigned* __restrict__ deg,
                               const int* __restrict__ batch,
                               unsigned short* __restrict__ hsh,
                               unsigned* __restrict__ pkw, int N) {
    int gtid = blockIdx.x * blockDim.x + threadIdx.x;
    int wave = gtid >> 6;
    int lane = threadIdx.x & 63;
    int half = lane >> 5;
    int l32  = lane & 31;
    int node = wave * 2 + half;
    if (node >= N) return;
    float4 xv = ((const float4*)(x + (size_t)node * 128))[l32];
    float4 wv = ((const float4*)W)[l32];
    float v = xv.x * wv.x + xv.y * wv.y + xv.z * wv.z + xv.w * wv.w;
    #pragma unroll
    for (int d = 16; d >= 1; d >>= 1) v += __shfl_xor(v, d);
    if (l32 == 0) {
        float di = rsqrtf((float)(deg[node] + 1u));
        hsh[node] = __half_as_ushort(__float2half(di * v));
        pkw[node] = ((unsigned)batch[node] << 16) | __half_as_ushort(__float2half(di));
    }
}

__global__ void pool_self_fb_kernel(const unsigned short* __restrict__ hsh,
                                    const unsigned* __restrict__ pkw,
                                    float* __restrict__ pooled, int N) {
    int i = blockIdx.x * blockDim.x + threadIdx.x;
    if (i >= N) return;
    unsigned w = pkw[i];
    float di = __half2float(__ushort_as_half((unsigned short)(w & 0xFFFFu)));
    atomicAdd(&pooled[w >> 16], di * __half2float(__ushort_as_half(hsh[i])));
}

__global__ void __launch_bounds__(512)
edge_direct_kernel(const int* __restrict__ src, const int* __restrict__ dst, int E,
                   const unsigned short* __restrict__ hsh,
                   const unsigned* __restrict__ pkw,
                   float* __restrict__ pooled) {
    __shared__ float pool[NUM_GRAPHS];
    for (int g = threadIdx.x; g < NUM_GRAPHS; g += 512) pool[g] = 0.0f;
    __syncthreads();
    int tid = blockIdx.x * 512 + threadIdx.x;
    int stride = gridDim.x * 512;
    for (int i = tid; i < E; i += stride) {
        unsigned w = pkw[dst[i]];
        float c = __half2float(__ushort_as_half(hsh[src[i]])) *
                  __half2float(__ushort_as_half((unsigned short)(w & 0xFFFFu)));
        atomicAdd(&pool[w >> 16], c);
    }
    __syncthreads();
    for (int g = threadIdx.x; g < NUM_GRAPHS; g += 512)
        if (pool[g] != 0.0f) atomicAdd(&pooled[g], pool[g]);
}

extern "C" void kernel_launch(void* const* d_in, const int* in_sizes, int n_in,
                              void* d_out, int out_size, void* d_ws, size_t ws_size,
                              hipStream_t stream) {
    const float* x    = (const float*)d_in[0];
    const float* W    = (const float*)d_in[1];
    const float* pp_w = (const float*)d_in[2];
    const float* pp_b = (const float*)d_in[3];
    const int*   ei   = (const int*)d_in[4];
    const int*   batch= (const int*)d_in[5];
    float* out = (float*)d_out;

    const int E = in_sizes[4] / 2;
    const int N = in_sizes[5];
    const int* src = ei;
    const int* dst = ei + E;
    int NBUK = (N + BSIZE - 1) >> BSHIFT;

    char* ws = (char*)d_ws;
    size_t off = 0;
    auto alloc = [&](size_t bytes) {
        size_t o = off; off = (off + bytes + 255) & ~(size_t)255; return o;
    };
    size_t h_off      = alloc((size_t)N * 4);     // also deg for fallback
    size_t hsh_off    = alloc((size_t)N * 2);
    size_t pkw_off    = alloc((size_t)N * 4);
    size_t pooled_off = alloc((size_t)NUM_GRAPHS * 4);
    size_t cursor_off = alloc((size_t)NGRP * 256 * 4);

    // per-(group,bucket) capacity: mean + 12.5% + 512 (≈17 sigma headroom)
    int meanG = E / (NBUK * NGRP) + 1;
    int capG = meanG + meanG / 8 + 512;
    size_t slab_off = alloc((size_t)NGRP * NBUK * (size_t)capG * 4);

    bool slab_ok = (NBUK <= 256) && (N <= (1 << 20)) && (off <= ws_size);

    float*          h      = (float*)(ws + h_off);
    unsigned*       deg    = (unsigned*)(ws + h_off);      // fallback alias
    unsigned short* hsh    = (unsigned short*)(ws + hsh_off);
    unsigned*       pkw    = (unsigned*)(ws + pkw_off);
    float*          pooled = (float*)(ws + pooled_off);
    unsigned*       cursor = (unsigned*)(ws + cursor_off);
    unsigned*       slab   = (unsigned*)(ws + slab_off);

    hipMemsetAsync(pooled, 0, (size_t)NUM_GRAPHS * 4, stream);

    if (slab_ok) {
        hipMemsetAsync(cursor, 0, (size_t)NGRP * 256 * 4, stream);
        int E4 = E >> 2;
        int nchunks = (E4 + (CHUNK / 4 - 1)) / (CHUNK / 4);
        int grid = nchunks < 2048 ? nchunks : 2048;
        pair_scatter_kernel<<<grid, 256, 0, stream>>>(src, dst, E, nchunks, NBUK,
                                                      capG, cursor, slab);
        int node_blocks = (N + 7) / 8;
        node_h_kernel<<<node_blocks, 256, 0, stream>>>(x, W, h, N);
        hist_finalize_kernel<<<NBUK, 1024, 0, stream>>>(slab, capG, cursor, h,
                                                        batch, hsh, pkw, N, NBUK);
        aggregate_kernel<<<NBUK, 1024, 0, stream>>>(slab, capG, cursor, pkw, hsh,
                                                    pooled, N, NBUK);
    } else {
        hipMemsetAsync(deg, 0, (size_t)N * 4, stream);
        deg_atomic_kernel<<<2048, 256, 0, stream>>>(dst, E, deg);
        int node_blocks = (N + 7) / 8;
        node_fb_kernel<<<node_blocks, 256, 0, stream>>>(x, W, deg, batch, hsh, pkw, N);
        pool_self_fb_kernel<<<(N + 255) / 256, 256, 0, stream>>>(hsh, pkw, pooled, N);
        edge_direct_kernel<<<512, 512, 0, stream>>>(src, dst, E, hsh, pkw, pooled);
    }

    out_kernel<<<(NUM_GRAPHS + 255) / 256, 256, 0, stream>>>(pooled, pp_w, pp_b, out);
}

// Round 9
// 305.332 us; speedup vs baseline: 1.1717x; 1.0355x over previous
//
#include <hip/hip_runtime.h>
#include <hip/hip_fp16.h>

#define NUM_GRAPHS 8192
#define BSHIFT 12
#define BSIZE 4096     // nodes per bucket
#define CHUNK 4096     // edges per chunk (23KB LDS -> 6 blocks/CU)
#define NGRP 32        // cursor/slab groups

// ===== Pass 1: h = x @ W (persistent waves, grid-stride, ILP) ==============
__global__ void node_h_kernel(const float* __restrict__ x,
                              const float* __restrict__ W,
                              float* __restrict__ h, int N) {
    int gwave = (blockIdx.x * blockDim.x + threadIdx.x) >> 6;
    int lane = threadIdx.x & 63;
    int half = lane >> 5;
    int l32  = lane & 31;
    int total_waves = (gridDim.x * blockDim.x) >> 6;
    float4 wv = ((const float4*)W)[l32];
    for (int node = gwave * 2 + half; node < N; node += total_waves * 2) {
        float4 xv = ((const float4*)(x + (size_t)node * 128))[l32];
        float v = xv.x * wv.x + xv.y * wv.y + xv.z * wv.z + xv.w * wv.w;
        #pragma unroll
        for (int d = 16; d >= 1; d >>= 1) v += __shfl_xor(v, d);
        if (l32 == 0) h[node] = v;
    }
}

// ===== Pass 2: scatter packed (dst_lo<<20 | src) into per-(group,bucket) ====
// sub-slabs. 23KB LDS -> 6 blocks/CU for latency hiding.
__global__ void __launch_bounds__(256)
pair_scatter_kernel(const int* __restrict__ src, const int* __restrict__ dst,
                    int E, int nchunks, int NBUK, int capG,
                    unsigned* __restrict__ cursor, unsigned* __restrict__ slab) {
    __shared__ unsigned cnt[256];
    __shared__ unsigned lbase[256];   // exclusive chunk-local base per bucket
    __shared__ unsigned sbase[256];   // global reservation base per bucket
    __shared__ unsigned staged[CHUNK];
    __shared__ unsigned char sbuck[CHUNK];
    __shared__ unsigned s_tot;

    const int4* s4 = (const int4*)src;
    const int4* d4 = (const int4*)dst;
    int E4 = E >> 2;
    int tid = threadIdx.x;
    int g = blockIdx.x & (NGRP - 1);

    for (int chunk = blockIdx.x; chunk < nchunks; chunk += gridDim.x) {
        cnt[tid] = 0; __syncthreads();
        int b4 = chunk * (CHUNK / 4);
        int4 vd[4], vs[4];
        unsigned short r[16];
        #pragma unroll
        for (int k = 0; k < 4; ++k) {
            int idx = b4 + k * 256 + tid;
            if (idx < E4) { vd[k] = d4[idx]; vs[k] = s4[idx]; }
            else          { vd[k] = make_int4(-1, -1, -1, -1); }
        }
        #pragma unroll
        for (int k = 0; k < 4; ++k) {
            if (vd[k].x >= 0) {
                r[4*k+0] = (unsigned short)atomicAdd(&cnt[vd[k].x >> BSHIFT], 1u);
                r[4*k+1] = (unsigned short)atomicAdd(&cnt[vd[k].y >> BSHIFT], 1u);
                r[4*k+2] = (unsigned short)atomicAdd(&cnt[vd[k].z >> BSHIFT], 1u);
                r[4*k+3] = (unsigned short)atomicAdd(&cnt[vd[k].w >> BSHIFT], 1u);
            }
        }
        __syncthreads();
        // inclusive Hillis-Steele scan of cnt -> lbase
        lbase[tid] = cnt[tid]; __syncthreads();
        #pragma unroll
        for (int off = 1; off < 256; off <<= 1) {
            unsigned a = (tid >= off) ? lbase[tid - off] : 0u;
            __syncthreads();
            lbase[tid] += a;
            __syncthreads();
        }
        if (tid == 255) s_tot = lbase[255];
        // reservation in group-private cursor row
        if (tid < NBUK && cnt[tid]) sbase[tid] = atomicAdd(&cursor[g * 256 + tid], cnt[tid]);
        unsigned excl = lbase[tid] - cnt[tid];
        __syncthreads();
        lbase[tid] = excl;
        __syncthreads();

        // stage entries bucket-sorted in LDS
        #pragma unroll
        for (int k = 0; k < 4; ++k) {
            if (vd[k].x >= 0) {
                int d0 = vd[k].x, d1 = vd[k].y, d2 = vd[k].z, d3 = vd[k].w;
                unsigned b0 = (unsigned)d0 >> BSHIFT, b1 = (unsigned)d1 >> BSHIFT;
                unsigned b2 = (unsigned)d2 >> BSHIFT, b3 = (unsigned)d3 >> BSHIFT;
                unsigned p0 = lbase[b0] + r[4*k+0];
                unsigned p1 = lbase[b1] + r[4*k+1];
                unsigned p2 = lbase[b2] + r[4*k+2];
                unsigned p3 = lbase[b3] + r[4*k+3];
                staged[p0] = ((unsigned)(d0 & (BSIZE - 1)) << 20) | (unsigned)vs[k].x;
                staged[p1] = ((unsigned)(d1 & (BSIZE - 1)) << 20) | (unsigned)vs[k].y;
                staged[p2] = ((unsigned)(d2 & (BSIZE - 1)) << 20) | (unsigned)vs[k].z;
                staged[p3] = ((unsigned)(d3 & (BSIZE - 1)) << 20) | (unsigned)vs[k].w;
                sbuck[p0] = (unsigned char)b0;
                sbuck[p1] = (unsigned char)b1;
                sbuck[p2] = (unsigned char)b2;
                sbuck[p3] = (unsigned char)b3;
            }
        }
        __syncthreads();

        // flush: consecutive lanes -> consecutive sub-slab addresses
        unsigned tot = s_tot;
        for (unsigned pos = tid; pos < tot; pos += 256) {
            unsigned b = sbuck[pos];
            unsigned gp = sbase[b] + (pos - lbase[b]);
            if (gp < (unsigned)capG)
                slab[((size_t)g * NBUK + b) * capG + gp] = staged[pos];
        }
        __syncthreads();
    }
    if (blockIdx.x == 0 && tid < (E & 3)) {
        int i = (E & ~3) + tid;
        int d = dst[i];
        unsigned b = (unsigned)d >> BSHIFT;
        unsigned p = atomicAdd(&cursor[b], 1u);   // group 0 row
        if (p < (unsigned)capG)
            slab[(size_t)b * capG + p] =
                ((unsigned)(d & (BSIZE - 1)) << 20) | (unsigned)src[i];
    }
}

// ===== Pass 3: per-bucket degree hist (over NGRP segments) -> hsh/pkw =======
__global__ void __launch_bounds__(1024)
hist_finalize_kernel(const unsigned* __restrict__ slab, int capG,
                     const unsigned* __restrict__ cursor,
                     const float* __restrict__ h, const int* __restrict__ batch,
                     unsigned short* __restrict__ hsh, unsigned* __restrict__ pkw,
                     int N, int NBUK) {
    __shared__ unsigned hist[BSIZE];
    int b = blockIdx.x, tid = threadIdx.x;
    for (int t = tid; t < BSIZE; t += 1024) hist[t] = 0;
    __syncthreads();
    for (int g = 0; g < NGRP; ++g) {
        unsigned n = cursor[g * 256 + b]; if (n > (unsigned)capG) n = capG;
        const unsigned* s = slab + ((size_t)g * NBUK + b) * capG;
        for (unsigned i = tid; i < n; i += 1024) atomicAdd(&hist[s[i] >> 20], 1u);
    }
    __syncthreads();
    int base = b << BSHIFT;
    int lim = N - base; if (lim > BSIZE) lim = BSIZE;
    for (int t = tid; t < lim; t += 1024) {
        float di = rsqrtf((float)(hist[t] + 1u));   // +1 self-loop
        hsh[base + t] = __half_as_ushort(__float2half(di * h[base + t]));
        pkw[base + t] = ((unsigned)batch[base + t] << 16) |
                        __half_as_ushort(__float2half(di));
    }
}

// ===== Pass 4: per-bucket aggregation (edges + self-loops) -> pooled ========
__global__ void __launch_bounds__(1024)
aggregate_kernel(const unsigned* __restrict__ slab, int capG,
                 const unsigned* __restrict__ cursor,
                 const unsigned* __restrict__ pkw,
                 const unsigned short* __restrict__ hsh,
                 float* __restrict__ pooled, int N, int NBUK) {
    __shared__ float pool[NUM_GRAPHS];
    __shared__ unsigned pkw_s[BSIZE];
    int b = blockIdx.x, tid = threadIdx.x;
    int base = b << BSHIFT;
    int lim = N - base; if (lim > BSIZE) lim = BSIZE;

    for (int t = tid; t < NUM_GRAPHS; t += 1024) pool[t] = 0.0f;
    for (int t = tid; t < BSIZE; t += 1024) pkw_s[t] = (t < lim) ? pkw[base + t] : 0u;
    __syncthreads();

    // self-loop terms
    for (int t = tid; t < lim; t += 1024) {
        unsigned w = pkw_s[t];
        float di = __half2float(__ushort_as_half((unsigned short)(w & 0xFFFFu)));
        float c = di * __half2float(__ushort_as_half(hsh[base + t]));
        atomicAdd(&pool[w >> 16], c);
    }

    // edge terms over the bucket's NGRP sub-slab segments
    for (int g = 0; g < NGRP; ++g) {
        unsigned n = cursor[g * 256 + b]; if (n > (unsigned)capG) n = capG;
        const unsigned* s = slab + ((size_t)g * NBUK + b) * capG;
        for (unsigned i = tid; i < n; i += 1024) {
            unsigned e = s[i];
            unsigned w = pkw_s[e >> 20];
            float hv = __half2float(__ushort_as_half(hsh[e & 0xFFFFFu]));
            float di = __half2float(__ushort_as_half((unsigned short)(w & 0xFFFFu)));
            atomicAdd(&pool[w >> 16], hv * di);
        }
    }
    __syncthreads();

    // batch sorted -> bucket spans [g_lo, g_hi]; flush only that range
    int g_lo = (int)(pkw_s[0] >> 16);
    int g_hi = (lim > 0) ? (int)(pkw_s[lim - 1] >> 16) : g_lo;
    for (int g = g_lo + tid; g <= g_hi; g += 1024) atomicAdd(&pooled[g], pool[g]);
}

// ===== Pass 5: affine ======================================================
__global__ void out_kernel(const float* __restrict__ pooled,
                           const float* __restrict__ pp_w,
                           const float* __restrict__ pp_b,
                           float* __restrict__ out) {
    int g = blockIdx.x * blockDim.x + threadIdx.x;
    if (g < NUM_GRAPHS) out[g] = pooled[g] * pp_w[0] + pp_b[0];
}

// ===== Fallback path (tiny ws / oversized N): correctness only =============
__global__ void deg_atomic_kernel(const int* __restrict__ dst, int E,
                                  unsigned* __restrict__ deg) {
    int tid = blockIdx.x * blockDim.x + threadIdx.x;
    int stride = gridDim.x * blockDim.x;
    for (int i = tid; i < E; i += stride) atomicAdd(&deg[dst[i]], 1u);
}

__global__ void node_fb_kernel(const float* __restrict__ x,
                               const float* __restrict__ W,
                               const unsigned* __restrict__ deg,
                               const int* __restrict__ batch,
                               unsigned short* __restrict__ hsh,
                               unsigned* __restrict__ pkw, int N) {
    int gtid = blockIdx.x * blockDim.x + threadIdx.x;
    int wave = gtid >> 6;
    int lane = threadIdx.x & 63;
    int half = lane >> 5;
    int l32  = lane & 31;
    int node = wave * 2 + half;
    if (node >= N) return;
    float4 xv = ((const float4*)(x + (size_t)node * 128))[l32];
    float4 wv = ((const float4*)W)[l32];
    float v = xv.x * wv.x + xv.y * wv.y + xv.z * wv.z + xv.w * wv.w;
    #pragma unroll
    for (int d = 16; d >= 1; d >>= 1) v += __shfl_xor(v, d);
    if (l32 == 0) {
        float di = rsqrtf((float)(deg[node] + 1u));
        hsh[node] = __half_as_ushort(__float2half(di * v));
        pkw[node] = ((unsigned)batch[node] << 16) | __half_as_ushort(__float2half(di));
    }
}

__global__ void pool_self_fb_kernel(const unsigned short* __restrict__ hsh,
                                    const unsigned* __restrict__ pkw,
                                    float* __restrict__ pooled, int N) {
    int i = blockIdx.x * blockDim.x + threadIdx.x;
    if (i >= N) return;
    unsigned w = pkw[i];
    float di = __half2float(__ushort_as_half((unsigned short)(w & 0xFFFFu)));
    atomicAdd(&pooled[w >> 16], di * __half2float(__ushort_as_half(hsh[i])));
}

__global__ void __launch_bounds__(512)
edge_direct_kernel(const int* __restrict__ src, const int* __restrict__ dst, int E,
                   const unsigned short* __restrict__ hsh,
                   const unsigned* __restrict__ pkw,
                   float* __restrict__ pooled) {
    __shared__ float pool[NUM_GRAPHS];
    for (int g = threadIdx.x; g < NUM_GRAPHS; g += 512) pool[g] = 0.0f;
    __syncthreads();
    int tid = blockIdx.x * 512 + threadIdx.x;
    int stride = gridDim.x * 512;
    for (int i = tid; i < E; i += stride) {
        unsigned w = pkw[dst[i]];
        float c = __half2float(__ushort_as_half(hsh[src[i]])) *
                  __half2float(__ushort_as_half((unsigned short)(w & 0xFFFFu)));
        atomicAdd(&pool[w >> 16], c);
    }
    __syncthreads();
    for (int g = threadIdx.x; g < NUM_GRAPHS; g += 512)
        if (pool[g] != 0.0f) atomicAdd(&pooled[g], pool[g]);
}

extern "C" void kernel_launch(void* const* d_in, const int* in_sizes, int n_in,
                              void* d_out, int out_size, void* d_ws, size_t ws_size,
                              hipStream_t stream) {
    const float* x    = (const float*)d_in[0];
    const float* W    = (const float*)d_in[1];
    const float* pp_w = (const float*)d_in[2];
    const float* pp_b = (const float*)d_in[3];
    const int*   ei   = (const int*)d_in[4];
    const int*   batch= (const int*)d_in[5];
    float* out = (float*)d_out;

    const int E = in_sizes[4] / 2;
    const int N = in_sizes[5];
    const int* src = ei;
    const int* dst = ei + E;
    int NBUK = (N + BSIZE - 1) >> BSHIFT;

    char* ws = (char*)d_ws;
    size_t off = 0;
    auto alloc = [&](size_t bytes) {
        size_t o = off; off = (off + bytes + 255) & ~(size_t)255; return o;
    };
    size_t h_off      = alloc((size_t)N * 4);     // also deg for fallback
    size_t hsh_off    = alloc((size_t)N * 2);
    size_t pkw_off    = alloc((size_t)N * 4);
    size_t pooled_off = alloc((size_t)NUM_GRAPHS * 4);
    size_t cursor_off = alloc((size_t)NGRP * 256 * 4);

    // per-(group,bucket) capacity: mean + 12.5% + 512 (≈17 sigma headroom)
    int meanG = E / (NBUK * NGRP) + 1;
    int capG = meanG + meanG / 8 + 512;
    size_t slab_off = alloc((size_t)NGRP * NBUK * (size_t)capG * 4);

    bool slab_ok = (NBUK <= 256) && (N <= (1 << 20)) && (off <= ws_size);

    float*          h      = (float*)(ws + h_off);
    unsigned*       deg    = (unsigned*)(ws + h_off);      // fallback alias
    unsigned short* hsh    = (unsigned short*)(ws + hsh_off);
    unsigned*       pkw    = (unsigned*)(ws + pkw_off);
    float*          pooled = (float*)(ws + pooled_off);
    unsigned*       cursor = (unsigned*)(ws + cursor_off);
    unsigned*       slab   = (unsigned*)(ws + slab_off);

    hipMemsetAsync(pooled, 0, (size_t)NUM_GRAPHS * 4, stream);

    if (slab_ok) {
        hipMemsetAsync(cursor, 0, (size_t)NGRP * 256 * 4, stream);
        int E4 = E >> 2;
        int nchunks = (E4 + (CHUNK / 4 - 1)) / (CHUNK / 4);
        int grid = nchunks < 4096 ? nchunks : 4096;
        pair_scatter_kernel<<<grid, 256, 0, stream>>>(src, dst, E, nchunks, NBUK,
                                                      capG, cursor, slab);
        node_h_kernel<<<8192, 256, 0, stream>>>(x, W, h, N);
        hist_finalize_kernel<<<NBUK, 1024, 0, stream>>>(slab, capG, cursor, h,
                                                        batch, hsh, pkw, N, NBUK);
        aggregate_kernel<<<NBUK, 1024, 0, stream>>>(slab, capG, cursor, pkw, hsh,
                                                    pooled, N, NBUK);
    } else {
        hipMemsetAsync(deg, 0, (size_t)N * 4, stream);
        deg_atomic_kernel<<<2048, 256, 0, stream>>>(dst, E, deg);
        int node_blocks = (N + 7) / 8;
        node_fb_kernel<<<node_blocks, 256, 0, stream>>>(x, W, deg, batch, hsh, pkw, N);
        pool_self_fb_kernel<<<(N + 255) / 256, 256, 0, stream>>>(hsh, pkw, pooled, N);
        edge_direct_kernel<<<512, 512, 0, stream>>>(src, dst, E, hsh, pkw, pooled);
    }

    out_kernel<<<(NUM_GRAPHS + 255) / 256, 256, 0, stream>>>(pooled, pp_w, pp_b, out);
}